// Round 11
// baseline (133.730 us; speedup 1.0000x reference)
//
#include <hip/hip_runtime.h>
#include <stdint.h>

// Problem constants (match reference.py)
#define P_IDS   50000
#define NBUCK   32                  // pid-range buckets
#define BUCK_W  1563                // ceil(50000/32) pids per bucket (fits 11 bits)
#define HPT     8                   // hits per thread in phase A
#define BLK_HITS (256 * HPT)        // 2048 hits per block
#define M_PER   64                  // record-slot cap per (bucket, block)
#define SUBB    8                   // blocks per bucket partition in phase B

// 8-byte record: x = (xi fp32 bits, low 11 mantissa bits = pid_local),
// y = fp32 bits of mse*xi. xi truncation rel-err <= 2^-12.
//
// Session lessons baked in:
//  - global fp32 atomics are memory-side (~32 B txn) regardless of scope -> 0 in hot path
//  - per-block __threadfence() = per-block L2 writeback, 512x serialized = +80 us -> never
//  - dispatch boundary is the cheap device-wide release (phaseA -> B -> C)
//  - register-batched loads beat per-hit load->wait->consume (MLP)
//  - LDS-staged compacted flush beats scattered 12 B global stores

// ---------------------------------------------------------------------------
// Phase A: streaming bucketer. No global atomics; records staged in LDS and
// flushed COMPACTED (wave 0 prefix-scans bucket counts; only valid records
// written). cnt_arr packs (offset<<16)|count. Block 0 zeroes d_out.
// ---------------------------------------------------------------------------
__global__ void __launch_bounds__(256)
phaseA_bucket(const float* __restrict__ beta,
              const float4* __restrict__ pred,
              const int* __restrict__ pid_arr,
              const float4* __restrict__ track,
              const int* __restrict__ recon,
              int* __restrict__ cnt_arr,     // [nblk][NBUCK]  (off<<16)|cnt
              uint2* __restrict__ recs,      // [nblk][2048] dense-compacted
              float* __restrict__ out,
              int n, int nblk) {
    __shared__ uint2 stage[NBUCK * M_PER];   // 16 KB
    __shared__ int cursor[NBUCK];
    __shared__ int prefx[NBUCK];
    const int t = threadIdx.x;
    if (t < NBUCK) cursor[t] = 0;
    if (blockIdx.x == 0 && t == 0) *out = 0.0f;
    __syncthreads();

    const int B = blockIdx.x * BLK_HITS;

    // ---- batch-load ALL hits into registers (max MLP) ----
    int    p_[HPT], r_[HPT];
    float  b_[HPT];
    float4 pr_[HPT], tp_[HPT];
    #pragma unroll
    for (int h = 0; h < HPT; ++h) {
        int i = B + h * 256 + t;
        if (i < n) {
            p_[h]  = pid_arr[i];
            r_[h]  = recon[i];
            b_[h]  = beta[i];
            pr_[h] = pred[i];
            tp_[h] = track[i];
        } else {
            p_[h] = 0; r_[h] = 0; b_[h] = 0.5f;
            pr_[h] = make_float4(0.f,0.f,0.f,0.f);
            tp_[h] = make_float4(0.f,0.f,0.f,0.f);
        }
    }

    // ---- compute + LDS scatter ----
    #pragma unroll
    for (int h = 0; h < HPT; ++h) {
        int p = p_[h], r = r_[h];
        if (r > 0 && p > 0) {
            float4 pr = pr_[h], tp = tp_[h];
            float dx = pr.x - tp.x, dy = pr.y - tp.y;
            float dz = pr.z - tp.z, dw = pr.w - tp.w;
            float mse = dx*dx + dy*dy + dz*dz + dw*dw;
            // arctanh(b) = 0.5*log((1+b)/(1-b)); b in (0.01,0.99) finite
            float at = 0.5f * logf((1.0f + b_[h]) / (1.0f - b_[h]));
            float xi = at * at;
            int bb = p / BUCK_W;               // 0..31 (magic-mul)
            int pl = p - bb * BUCK_W;          // 0..1562, fits 11 bits
            int rank = atomicAdd(&cursor[bb], 1);    // LDS atomic only
            if (rank < M_PER) {
                uint2 rr;
                rr.x = (__float_as_uint(xi) & 0xFFFFF800u) | (uint32_t)pl;
                rr.y = __float_as_uint(mse * xi);
                stage[bb * M_PER + rank] = rr;       // LDS scatter (cheap)
            }
        }
    }
    __syncthreads();

    // ---- wave 0: exclusive prefix scan of bucket counts; emit descriptors ----
    if (t < 64) {
        int c = (t < NBUCK) ? min(cursor[t], M_PER) : 0;
        int x = c;
        #pragma unroll
        for (int d = 1; d < NBUCK; d <<= 1) {
            int y = __shfl_up(x, d, 64);
            if (t >= d) x += y;
        }
        if (t < NBUCK) {
            int excl = x - c;
            prefx[t] = excl;
            cnt_arr[blockIdx.x * NBUCK + t] = (excl << 16) | c;
        }
    }
    __syncthreads();

    // ---- compacted flush: only valid records, dense within the block ----
    uint2* dst = recs + (size_t)blockIdx.x * (NBUCK * M_PER);
    #pragma unroll
    for (int k = 0; k < 8; ++k) {
        int slot = t + k * 256;
        int bb = slot >> 6, rank = slot & 63;
        if (rank < min(cursor[bb], M_PER))
            dst[prefx[bb] + rank] = stage[slot];
    }
}

// ---------------------------------------------------------------------------
// Phase B: blockIdx = part*SUBB + sub. Private LDS histogram of the
// partition's 1563 pids. Half-wave pairing (lanes 0-31 / 32-63 walk separate
// region streams) + DESCRIPTOR PREFETCH: each lane pre-loads the descriptor
// for its half's k-th future region; the region loop pulls it from a register
// via __shfl, so the per-region dependent chain is records-load -> LDS atomic
// only. No fences — the dispatch boundary publishes the partials.
// ---------------------------------------------------------------------------
__global__ void __launch_bounds__(256)
phaseB_bin(const int* __restrict__ cnt_arr,
           const uint2* __restrict__ recs,
           float2* __restrict__ partials,    // [NBUCK*SUBB][BUCK_W]
           int nblk) {
    __shared__ float2 hist[BUCK_W];   // 12.5 KB
    int part = blockIdx.x / SUBB;
    int sub  = blockIdx.x % SUBB;

    for (int j = threadIdx.x; j < BUCK_W; j += 256)
        hist[j] = make_float2(0.0f, 0.0f);

    int lane   = threadIdx.x & 63;
    int half   = lane >> 5;               // 0/1
    int hlane  = lane & 31;
    int wid    = threadIdx.x >> 6;
    int wslot  = sub * 4 + wid;           // 0 .. SUBB*4-1 (0..31)
    int stream = wslot * 2 + half;        // 0 .. 63 region streams
    const int nstreams = SUBB * 4 * 2;    // 64

    // Prefetch: lane with hlane==k holds the descriptor for its half's k-th
    // region (region = stream + k*nstreams). K = ceil(nblk/64) <= 16 < 32.
    int myreg  = (wslot * 2 + half) + hlane * nstreams;
    int mydesc = (myreg < nblk) ? cnt_arr[myreg * NBUCK + part] : 0;

    __syncthreads();   // hist init done (placed after prefetch issue)

    for (int k = 0; ; ++k) {
        int region = stream + k * nstreams;
        if (!__any(region < nblk)) break;
        int pc = __shfl(mydesc, (lane & 32) + k, 64);   // src lane = half*32+k
        if (region < nblk) {
            int off = pc >> 16, cnt = pc & 0xFFFF;
            const uint2* r = recs + (size_t)region * (NBUCK * M_PER) + off;
            for (int idx = hlane; idx < cnt; idx += 32) {
                uint2 rr = r[idx];
                int   pl  = rr.x & 0x7FFu;
                float xi  = __uint_as_float(rr.x & 0xFFFFF800u);
                float num = __uint_as_float(rr.y);
                atomicAdd(&hist[pl].x, num);   // LDS atomic
                atomicAdd(&hist[pl].y, xi);
            }
        }
    }
    __syncthreads();

    float2* dst = partials + (size_t)blockIdx.x * BUCK_W;
    for (int j = threadIdx.x; j < BUCK_W; j += 256)
        dst[j] = hist[j];
}

// ---------------------------------------------------------------------------
// Phase C: per pid sum the SUBB partials, ratio in fp32 (keeps 0/0 -> NaN
// reference semantics), double accumulation, wave64 reduce, one atomic/block.
// ---------------------------------------------------------------------------
__global__ void __launch_bounds__(256)
phaseC_mean(const float2* __restrict__ partials,
            float* __restrict__ out) {
    double local = 0.0;
    int stride = gridDim.x * blockDim.x;
    for (int p = 1 + blockIdx.x * blockDim.x + threadIdx.x; p < P_IDS; p += stride) {
        int part = p / BUCK_W;
        int loc  = p % BUCK_W;
        const float2* base = partials + ((size_t)part * SUBB) * BUCK_W + loc;
        float num = 0.0f, den = 0.0f;
        #pragma unroll
        for (int s = 0; s < SUBB; ++s) {
            float2 v = base[(size_t)s * BUCK_W];
            num += v.x;
            den += v.y;
        }
        local += (double)(num / den);
    }

    for (int off = 32; off > 0; off >>= 1)
        local += __shfl_down(local, off, 64);

    __shared__ double wave_sums[4];
    int lane = threadIdx.x & 63;
    int wid  = threadIdx.x >> 6;
    if (lane == 0) wave_sums[wid] = local;
    __syncthreads();

    if (threadIdx.x == 0) {
        double s = wave_sums[0] + wave_sums[1] + wave_sums[2] + wave_sums[3];
        atomicAdd(out, (float)(s / (double)(P_IDS - 1)));
    }
}

// ---------------------------------------------------------------------------
// Fallback path (ws too small): direct device-atomic scatter.
// ---------------------------------------------------------------------------
__global__ void __launch_bounds__(256)
scatter_fallback(const float* __restrict__ beta,
                 const float4* __restrict__ pred,
                 const int* __restrict__ pid,
                 const float4* __restrict__ track,
                 const int* __restrict__ recon,
                 float2* __restrict__ bins, int n) {
    int i = blockIdx.x * blockDim.x + threadIdx.x;
    if (i >= n) return;
    int p = pid[i];
    int r = recon[i];
    if (r <= 0 || p <= 0) return;
    float  b  = beta[i];
    float4 pr = pred[i];
    float4 tp = track[i];
    float dx = pr.x - tp.x, dy = pr.y - tp.y, dz = pr.z - tp.z, dw = pr.w - tp.w;
    float mse = dx*dx + dy*dy + dz*dz + dw*dw;
    float at = 0.5f * logf((1.0f + b) / (1.0f - b));
    float xi = at * at;
    atomicAdd(&bins[p].x, mse * xi);
    atomicAdd(&bins[p].y, xi);
}

__global__ void __launch_bounds__(256)
reduce_fallback(const float2* __restrict__ bins, float* __restrict__ out) {
    double local = 0.0;
    int stride = gridDim.x * blockDim.x;
    for (int p = 1 + blockIdx.x * blockDim.x + threadIdx.x; p < P_IDS; p += stride) {
        float2 v = bins[p];
        local += (double)(v.x / v.y);
    }
    for (int off = 32; off > 0; off >>= 1)
        local += __shfl_down(local, off, 64);
    __shared__ double wave_sums[4];
    int lane = threadIdx.x & 63;
    int wid  = threadIdx.x >> 6;
    if (lane == 0) wave_sums[wid] = local;
    __syncthreads();
    if (threadIdx.x == 0) {
        double s = wave_sums[0] + wave_sums[1] + wave_sums[2] + wave_sums[3];
        atomicAdd(out, (float)(s / (double)(P_IDS - 1)));
    }
}

extern "C" void kernel_launch(void* const* d_in, const int* in_sizes, int n_in,
                              void* d_out, int out_size, void* d_ws, size_t ws_size,
                              hipStream_t stream) {
    // setup_inputs() order: beta, pred, particle_id, track_params, reconstructable
    const float*  beta  = (const float*)d_in[0];
    const float4* pred  = (const float4*)d_in[1];
    const int*    pid   = (const int*)d_in[2];
    const float4* track = (const float4*)d_in[3];
    const int*    recon = (const int*)d_in[4];
    float* out = (float*)d_out;
    int n = in_sizes[0];

    int nblk = (n + BLK_HITS - 1) / BLK_HITS;   // 977 for N=2e6

    // ws layout: [recs][cnt_arr][partials], all 256 B aligned
    size_t recs_bytes = sizeof(uint2) * (size_t)nblk * NBUCK * M_PER;   // ~15.6 MB
    size_t recs_pad   = (recs_bytes + 255) & ~(size_t)255;
    size_t cnt_bytes  = sizeof(int) * (size_t)nblk * NBUCK;             // ~125 KB
    size_t cnt_pad    = (cnt_bytes + 255) & ~(size_t)255;
    size_t part_bytes = sizeof(float2) * (size_t)NBUCK * SUBB * BUCK_W; // ~3.2 MB
    size_t needed = recs_pad + cnt_pad + part_bytes;

    if (ws_size >= needed) {
        uint2*  recs     = (uint2*)d_ws;
        int*    cnt_arr  = (int*)((char*)d_ws + recs_pad);
        float2* partials = (float2*)((char*)d_ws + recs_pad + cnt_pad);

        phaseA_bucket<<<nblk, 256, 0, stream>>>(beta, pred, pid, track, recon,
                                                cnt_arr, recs, out, n, nblk);
        phaseB_bin<<<NBUCK * SUBB, 256, 0, stream>>>(cnt_arr, recs, partials, nblk);
        phaseC_mean<<<196, 256, 0, stream>>>(partials, out);
    } else {
        // Fallback: direct atomic scatter into float2 bins (400 KB)
        float2* bins = (float2*)d_ws;
        hipMemsetAsync(bins, 0, P_IDS * sizeof(float2), stream);
        hipMemsetAsync(d_out, 0, sizeof(float), stream);
        int grid = (n + 255) / 256;
        scatter_fallback<<<grid, 256, 0, stream>>>(beta, pred, pid, track, recon,
                                                   bins, n);
        reduce_fallback<<<196, 256, 0, stream>>>(bins, out);
    }
}

// Round 12
// 130.820 us; speedup vs baseline: 1.0222x; 1.0222x over previous
//
#include <hip/hip_runtime.h>
#include <stdint.h>

// Problem constants (match reference.py)
#define P_IDS   50000
#define NBUCK   32                  // pid-range buckets
#define BUCK_W  1563                // ceil(50000/32) pids per bucket (fits 11 bits)
#define HPT     8                   // hits per thread in phase A
#define BLK_HITS (256 * HPT)        // 2048 hits per block
#define M_PER   64                  // record-slot cap per (bucket, block)
#define SUBB    16                  // blocks per bucket partition in phase B

// 8-byte record: x = (xi fp32 bits, low 11 mantissa bits = pid_local),
// y = fp32 bits of mse*xi. xi truncation rel-err <= 2^-12.
//
// Session lessons baked in (measured, this session):
//  - global fp32 atomics are memory-side (~32 B txn) regardless of scope -> 0 in hot path
//  - per-block __threadfence() = per-block L2 writeback, 512x serialized = +80 us -> never
//  - dispatch boundary is the cheap device-wide release (phaseA -> B -> C)
//  - register-batched loads beat per-hit load->wait->consume (MLP), R8: -3.6 us
//  - LDS-staged compacted flush beats scattered 12 B global stores, R7: -5.2 us
//  - phaseB needs >=2 blocks/CU (SUBB=16); SUBB=8 + shfl descriptor prefetch
//    regressed +2.8 us (R11) — parallelism beats traffic in the latency tail

// ---------------------------------------------------------------------------
// Phase A: streaming bucketer. No global atomics; records staged in LDS and
// flushed COMPACTED (wave 0 prefix-scans bucket counts; only valid records
// written). cnt_arr packs (offset<<16)|count. Block 0 zeroes d_out (visible
// to phaseC via dispatch-boundary release).
// ---------------------------------------------------------------------------
__global__ void __launch_bounds__(256)
phaseA_bucket(const float* __restrict__ beta,
              const float4* __restrict__ pred,
              const int* __restrict__ pid_arr,
              const float4* __restrict__ track,
              const int* __restrict__ recon,
              int* __restrict__ cnt_arr,     // [nblk][NBUCK]  (off<<16)|cnt
              uint2* __restrict__ recs,      // [nblk][2048] dense-compacted
              float* __restrict__ out,
              int n, int nblk) {
    __shared__ uint2 stage[NBUCK * M_PER];   // 16 KB
    __shared__ int cursor[NBUCK];
    __shared__ int prefx[NBUCK];
    const int t = threadIdx.x;
    if (t < NBUCK) cursor[t] = 0;
    if (blockIdx.x == 0 && t == 0) *out = 0.0f;
    __syncthreads();

    const int B = blockIdx.x * BLK_HITS;

    // ---- batch-load ALL hits into registers (max MLP) ----
    int    p_[HPT], r_[HPT];
    float  b_[HPT];
    float4 pr_[HPT], tp_[HPT];
    #pragma unroll
    for (int h = 0; h < HPT; ++h) {
        int i = B + h * 256 + t;
        if (i < n) {
            p_[h]  = pid_arr[i];
            r_[h]  = recon[i];
            b_[h]  = beta[i];
            pr_[h] = pred[i];
            tp_[h] = track[i];
        } else {
            p_[h] = 0; r_[h] = 0; b_[h] = 0.5f;
            pr_[h] = make_float4(0.f,0.f,0.f,0.f);
            tp_[h] = make_float4(0.f,0.f,0.f,0.f);
        }
    }

    // ---- compute + LDS scatter ----
    #pragma unroll
    for (int h = 0; h < HPT; ++h) {
        int p = p_[h], r = r_[h];
        if (r > 0 && p > 0) {
            float4 pr = pr_[h], tp = tp_[h];
            float dx = pr.x - tp.x, dy = pr.y - tp.y;
            float dz = pr.z - tp.z, dw = pr.w - tp.w;
            float mse = dx*dx + dy*dy + dz*dz + dw*dw;
            // arctanh(b) = 0.5*log((1+b)/(1-b)); b in (0.01,0.99) finite
            float at = 0.5f * logf((1.0f + b_[h]) / (1.0f - b_[h]));
            float xi = at * at;
            int bb = p / BUCK_W;               // 0..31 (magic-mul)
            int pl = p - bb * BUCK_W;          // 0..1562, fits 11 bits
            int rank = atomicAdd(&cursor[bb], 1);    // LDS atomic only
            if (rank < M_PER) {
                uint2 rr;
                rr.x = (__float_as_uint(xi) & 0xFFFFF800u) | (uint32_t)pl;
                rr.y = __float_as_uint(mse * xi);
                stage[bb * M_PER + rank] = rr;       // LDS scatter (cheap)
            }
        }
    }
    __syncthreads();

    // ---- wave 0: exclusive prefix scan of bucket counts; emit descriptors ----
    if (t < 64) {
        int c = (t < NBUCK) ? min(cursor[t], M_PER) : 0;
        int x = c;
        #pragma unroll
        for (int d = 1; d < NBUCK; d <<= 1) {
            int y = __shfl_up(x, d, 64);
            if (t >= d) x += y;
        }
        if (t < NBUCK) {
            int excl = x - c;
            prefx[t] = excl;
            cnt_arr[blockIdx.x * NBUCK + t] = (excl << 16) | c;
        }
    }
    __syncthreads();

    // ---- compacted flush: only valid records, dense within the block ----
    uint2* dst = recs + (size_t)blockIdx.x * (NBUCK * M_PER);
    #pragma unroll
    for (int k = 0; k < 8; ++k) {
        int slot = t + k * 256;
        int bb = slot >> 6, rank = slot & 63;
        if (rank < min(cursor[bb], M_PER))
            dst[prefx[bb] + rank] = stage[slot];
    }
}

// ---------------------------------------------------------------------------
// Phase B: blockIdx = part*SUBB + sub. Private LDS histogram of the
// partition's 1563 pids; HALF-WAVE PAIRING: lanes 0-31 and 32-63 each walk a
// different source block's (dense) region -> full lane utilization, half the
// dependent descriptor->records latency trips. Partial histogram written to
// global at the end. No fences — the dispatch boundary publishes.
// ---------------------------------------------------------------------------
__global__ void __launch_bounds__(256)
phaseB_bin(const int* __restrict__ cnt_arr,
           const uint2* __restrict__ recs,
           float2* __restrict__ partials,    // [NBUCK*SUBB][BUCK_W]
           int nblk) {
    __shared__ float2 hist[BUCK_W];   // 12.5 KB
    int part = blockIdx.x / SUBB;
    int sub  = blockIdx.x % SUBB;

    for (int j = threadIdx.x; j < BUCK_W; j += 256)
        hist[j] = make_float2(0.0f, 0.0f);
    __syncthreads();

    int lane  = threadIdx.x & 63;
    int half  = lane >> 5;                // 0/1: which source block of the pair
    int hlane = lane & 31;
    int wid   = threadIdx.x >> 6;
    int wslot = sub * 4 + wid;            // 0 .. SUBB*4-1
    const int nslots = SUBB * 4;

    for (int bp = wslot * 2; bp < nblk; bp += nslots * 2) {
        int b = bp + half;
        if (b < nblk) {
            int pc  = cnt_arr[b * NBUCK + part];
            int off = pc >> 16, cnt = pc & 0xFFFF;
            const uint2* r = recs + (size_t)b * (NBUCK * M_PER) + off;
            for (int idx = hlane; idx < cnt; idx += 32) {
                uint2 rr = r[idx];
                int   pl  = rr.x & 0x7FFu;
                float xi  = __uint_as_float(rr.x & 0xFFFFF800u);
                float num = __uint_as_float(rr.y);
                atomicAdd(&hist[pl].x, num);   // LDS atomic
                atomicAdd(&hist[pl].y, xi);
            }
        }
    }
    __syncthreads();

    float2* dst = partials + (size_t)blockIdx.x * BUCK_W;
    for (int j = threadIdx.x; j < BUCK_W; j += 256)
        dst[j] = hist[j];
}

// ---------------------------------------------------------------------------
// Phase C: per pid sum the SUBB partials, ratio in fp32 (keeps 0/0 -> NaN
// reference semantics), double accumulation, wave64 reduce, one atomic/block.
// ---------------------------------------------------------------------------
__global__ void __launch_bounds__(256)
phaseC_mean(const float2* __restrict__ partials,
            float* __restrict__ out) {
    double local = 0.0;
    int stride = gridDim.x * blockDim.x;
    for (int p = 1 + blockIdx.x * blockDim.x + threadIdx.x; p < P_IDS; p += stride) {
        int part = p / BUCK_W;
        int loc  = p % BUCK_W;
        const float2* base = partials + ((size_t)part * SUBB) * BUCK_W + loc;
        float num = 0.0f, den = 0.0f;
        #pragma unroll
        for (int s = 0; s < SUBB; ++s) {
            float2 v = base[(size_t)s * BUCK_W];
            num += v.x;
            den += v.y;
        }
        local += (double)(num / den);
    }

    for (int off = 32; off > 0; off >>= 1)
        local += __shfl_down(local, off, 64);

    __shared__ double wave_sums[4];
    int lane = threadIdx.x & 63;
    int wid  = threadIdx.x >> 6;
    if (lane == 0) wave_sums[wid] = local;
    __syncthreads();

    if (threadIdx.x == 0) {
        double s = wave_sums[0] + wave_sums[1] + wave_sums[2] + wave_sums[3];
        atomicAdd(out, (float)(s / (double)(P_IDS - 1)));
    }
}

// ---------------------------------------------------------------------------
// Fallback path (ws too small): direct device-atomic scatter.
// ---------------------------------------------------------------------------
__global__ void __launch_bounds__(256)
scatter_fallback(const float* __restrict__ beta,
                 const float4* __restrict__ pred,
                 const int* __restrict__ pid,
                 const float4* __restrict__ track,
                 const int* __restrict__ recon,
                 float2* __restrict__ bins, int n) {
    int i = blockIdx.x * blockDim.x + threadIdx.x;
    if (i >= n) return;
    int p = pid[i];
    int r = recon[i];
    if (r <= 0 || p <= 0) return;
    float  b  = beta[i];
    float4 pr = pred[i];
    float4 tp = track[i];
    float dx = pr.x - tp.x, dy = pr.y - tp.y, dz = pr.z - tp.z, dw = pr.w - tp.w;
    float mse = dx*dx + dy*dy + dz*dz + dw*dw;
    float at = 0.5f * logf((1.0f + b) / (1.0f - b));
    float xi = at * at;
    atomicAdd(&bins[p].x, mse * xi);
    atomicAdd(&bins[p].y, xi);
}

__global__ void __launch_bounds__(256)
reduce_fallback(const float2* __restrict__ bins, float* __restrict__ out) {
    double local = 0.0;
    int stride = gridDim.x * blockDim.x;
    for (int p = 1 + blockIdx.x * blockDim.x + threadIdx.x; p < P_IDS; p += stride) {
        float2 v = bins[p];
        local += (double)(v.x / v.y);
    }
    for (int off = 32; off > 0; off >>= 1)
        local += __shfl_down(local, off, 64);
    __shared__ double wave_sums[4];
    int lane = threadIdx.x & 63;
    int wid  = threadIdx.x >> 6;
    if (lane == 0) wave_sums[wid] = local;
    __syncthreads();
    if (threadIdx.x == 0) {
        double s = wave_sums[0] + wave_sums[1] + wave_sums[2] + wave_sums[3];
        atomicAdd(out, (float)(s / (double)(P_IDS - 1)));
    }
}

extern "C" void kernel_launch(void* const* d_in, const int* in_sizes, int n_in,
                              void* d_out, int out_size, void* d_ws, size_t ws_size,
                              hipStream_t stream) {
    // setup_inputs() order: beta, pred, particle_id, track_params, reconstructable
    const float*  beta  = (const float*)d_in[0];
    const float4* pred  = (const float4*)d_in[1];
    const int*    pid   = (const int*)d_in[2];
    const float4* track = (const float4*)d_in[3];
    const int*    recon = (const int*)d_in[4];
    float* out = (float*)d_out;
    int n = in_sizes[0];

    int nblk = (n + BLK_HITS - 1) / BLK_HITS;   // 977 for N=2e6

    // ws layout: [recs][cnt_arr][partials], all 256 B aligned
    size_t recs_bytes = sizeof(uint2) * (size_t)nblk * NBUCK * M_PER;   // ~15.6 MB
    size_t recs_pad   = (recs_bytes + 255) & ~(size_t)255;
    size_t cnt_bytes  = sizeof(int) * (size_t)nblk * NBUCK;             // ~125 KB
    size_t cnt_pad    = (cnt_bytes + 255) & ~(size_t)255;
    size_t part_bytes = sizeof(float2) * (size_t)NBUCK * SUBB * BUCK_W; // ~6.4 MB
    size_t needed = recs_pad + cnt_pad + part_bytes;

    if (ws_size >= needed) {
        uint2*  recs     = (uint2*)d_ws;
        int*    cnt_arr  = (int*)((char*)d_ws + recs_pad);
        float2* partials = (float2*)((char*)d_ws + recs_pad + cnt_pad);

        phaseA_bucket<<<nblk, 256, 0, stream>>>(beta, pred, pid, track, recon,
                                                cnt_arr, recs, out, n, nblk);
        phaseB_bin<<<NBUCK * SUBB, 256, 0, stream>>>(cnt_arr, recs, partials, nblk);
        phaseC_mean<<<196, 256, 0, stream>>>(partials, out);
    } else {
        // Fallback: direct atomic scatter into float2 bins (400 KB)
        float2* bins = (float2*)d_ws;
        hipMemsetAsync(bins, 0, P_IDS * sizeof(float2), stream);
        hipMemsetAsync(d_out, 0, sizeof(float), stream);
        int grid = (n + 255) / 256;
        scatter_fallback<<<grid, 256, 0, stream>>>(beta, pred, pid, track, recon,
                                                   bins, n);
        reduce_fallback<<<196, 256, 0, stream>>>(bins, out);
    }
}